// Round 3
// baseline (1410.426 us; speedup 1.0000x reference)
//
#include <hip/hip_runtime.h>
#include <math.h>

#define NB   8
#define NPTS 4096
#define MPER 1024
#define MTOT (NB*MPER)
#define CIN  64
#define KNN  64
#define CAP  512
// (0.2*0.2) computed in double, as the reference's python-float R*R
#define R2D  0.04000000000000001

typedef float v2f __attribute__((ext_vector_type(2)));
typedef unsigned int u32;
typedef unsigned long long u64;

// exact IEEE fp32 distance, reference order: ((dx*dx + dy*dy) + dz*dz), no FMA
__device__ __forceinline__ float d2f(float ax, float ay, float az,
                                     float bx, float by, float bz) {
    float dx = __fsub_rn(ax, bx);
    float dy = __fsub_rn(ay, by);
    float dz = __fsub_rn(az, bz);
    return __fadd_rn(__fadd_rn(__fmul_rn(dx, dx), __fmul_rn(dy, dy)),
                     __fmul_rn(dz, dz));
}

// CDNA packed 2xFP32 ops — IEEE-identical per component, and being asm they
// can never be FMA-contracted.
__device__ __forceinline__ v2f pk_add(v2f a, v2f b) {
    v2f d;
    asm("v_pk_add_f32 %0, %1, %2" : "=v"(d) : "v"(a), "v"(b));
    return d;
}
__device__ __forceinline__ v2f pk_mul(v2f a, v2f b) {
    v2f d;
    asm("v_pk_mul_f32 %0, %1, %2" : "=v"(d) : "v"(a), "v"(b));
    return d;
}

// ---------------- Kernel 1: farthest point sampling ----------------
// one block per cloud; 256 threads (4 waves), 16 points/thread in registers
// (8 packed pairs). Per iteration: packed distance/min update -> local argmax
// -> DPP wave argmax carrying (key, x, y, z) payload -> 1 barrier ->
// redundant 4-way cross-wave select (payload included, no dependent reads).
__global__ __launch_bounds__(256) void fps_kernel(const float* __restrict__ pos,
                                                  int* __restrict__ sel)
{
    const int b    = blockIdx.x;
    const int t    = threadIdx.x;
    const int lane = t & 63;
    const int wv   = t >> 6;
    const float* pb = pos + (size_t)b * NPTS * 3;

    __shared__ u64   skey[2][4];
    __shared__ float sxp[2][4], syp[2][4], szp[2][4];

    v2f px[8], py[8], pz[8], mind[8];
#pragma unroll
    for (int pr = 0; pr < 8; ++pr) {
        int j0 = (2 * pr + 0) * 256 + t;
        int j1 = (2 * pr + 1) * 256 + t;
        px[pr] = v2f{pb[j0 * 3 + 0], pb[j1 * 3 + 0]};
        py[pr] = v2f{pb[j0 * 3 + 1], pb[j1 * 3 + 1]};
        pz[pr] = v2f{pb[j0 * 3 + 2], pb[j1 * 3 + 2]};
        mind[pr] = v2f{3.0e38f, 3.0e38f};   // first fmin yields exactly d2-to-p0
    }
    if (t == 0) sel[b * MPER + 0] = b * NPTS + 0;

    // initial centroid = point 0 (uniform scalar load)
    float cx = pb[0], cy = pb[1], cz = pb[2];

    for (int it = 1; it < MPER; ++it) {
        const v2f ncx = v2f{-cx, -cx};
        const v2f ncy = v2f{-cy, -cy};
        const v2f ncz = v2f{-cz, -cz};

        // local argmax of updated min-dists (ascending j + strict > keeps the
        // lowest index on ties, matching jnp.argmax); coords tracked via bi.
        float bv = -1.0f; int bi = 0;
        float bx = 0.f, by = 0.f, bz = 0.f;
#pragma unroll
        for (int pr = 0; pr < 8; ++pr) {
            v2f dx = pk_add(px[pr], ncx);          // p - c exactly (a+(-b)==a-b)
            v2f dy = pk_add(py[pr], ncy);
            v2f dz = pk_add(pz[pr], ncz);
            v2f s  = pk_add(pk_mul(dx, dx), pk_mul(dy, dy));
            v2f d2 = pk_add(s, pk_mul(dz, dz));    // ((dx^2+dy^2)+dz^2), exact order
            float m0 = fminf(mind[pr].x, d2.x);
            float m1 = fminf(mind[pr].y, d2.y);
            mind[pr].x = m0; mind[pr].y = m1;
            if (m0 > bv) { bv = m0; bi = (2 * pr + 0) * 256 + t;
                           bx = px[pr].x; by = py[pr].x; bz = pz[pr].x; }
            if (m1 > bv) { bv = m1; bi = (2 * pr + 1) * 256 + t;
                           bx = px[pr].y; by = py[pr].y; bz = pz[pr].y; }
        }

        // pack (d2 bits, ~idx): max key == (max d2, then min idx). d2 >= 0 so
        // float bits are order-isomorphic; key is always > 0.
        u32 kl = (u32)(~bi);
        u32 kh = __float_as_uint(bv);
        float wx = bx, wy = by, wz = bz;

        // 64-lane DPP argmax with payload; final in lane 63.
#define DPPSTEP(ctrl, rmask)                                                    \
        do {                                                                    \
            u32 plo = (u32)__builtin_amdgcn_update_dpp(0, (int)kl, ctrl, rmask, 0xf, false); \
            u32 phi = (u32)__builtin_amdgcn_update_dpp(0, (int)kh, ctrl, rmask, 0xf, false); \
            int qxi = __builtin_amdgcn_update_dpp(0, __float_as_int(wx), ctrl, rmask, 0xf, false); \
            int qyi = __builtin_amdgcn_update_dpp(0, __float_as_int(wy), ctrl, rmask, 0xf, false); \
            int qzi = __builtin_amdgcn_update_dpp(0, __float_as_int(wz), ctrl, rmask, 0xf, false); \
            u64 pk = ((u64)phi << 32) | plo;                                    \
            u64 ck = ((u64)kh << 32) | kl;                                      \
            if (pk > ck) { kl = plo; kh = phi;                                  \
                           wx = __int_as_float(qxi);                            \
                           wy = __int_as_float(qyi);                            \
                           wz = __int_as_float(qzi); }                          \
        } while (0)
        DPPSTEP(0x111, 0xf);   // row_shr:1
        DPPSTEP(0x112, 0xf);   // row_shr:2
        DPPSTEP(0x114, 0xf);   // row_shr:4
        DPPSTEP(0x118, 0xf);   // row_shr:8
        DPPSTEP(0x142, 0xa);   // row_bcast:15 -> rows 1,3
        DPPSTEP(0x143, 0xc);   // row_bcast:31 -> rows 2,3
#undef DPPSTEP

        const int p = it & 1;
        if (lane == 63) {
            skey[p][wv] = ((u64)kh << 32) | kl;
            sxp[p][wv] = wx; syp[p][wv] = wy; szp[p][wv] = wz;
        }
        __syncthreads();

        u64   K0 = skey[p][0], K1 = skey[p][1], K2 = skey[p][2], K3 = skey[p][3];
        float X0 = sxp[p][0], X1 = sxp[p][1], X2 = sxp[p][2], X3 = sxp[p][3];
        float Y0 = syp[p][0], Y1 = syp[p][1], Y2 = syp[p][2], Y3 = syp[p][3];
        float Z0 = szp[p][0], Z1 = szp[p][1], Z2 = szp[p][2], Z3 = szp[p][3];
        u64 Ka; float Xa, Ya, Za;
        if (K1 > K0) { Ka = K1; Xa = X1; Ya = Y1; Za = Z1; }
        else         { Ka = K0; Xa = X0; Ya = Y0; Za = Z0; }
        u64 Kb; float Xb, Yb, Zb;
        if (K3 > K2) { Kb = K3; Xb = X3; Yb = Y3; Zb = Z3; }
        else         { Kb = K2; Xb = X2; Yb = Y2; Zb = Z2; }
        u64 Kf; 
        if (Kb > Ka) { Kf = Kb; cx = Xb; cy = Yb; cz = Zb; }
        else         { Kf = Ka; cx = Xa; cy = Ya; cz = Za; }

        if (t == 0) {
            int pick = (int)(~(u32)Kf);
            sel[b * MPER + it] = b * NPTS + pick;
        }
    }
}

// ---------------- Kernel 2: ball query + K nearest (rank select) ----------------
// one wave per centroid, 4 waves / block
__global__ __launch_bounds__(256) void ballq_kernel(
    const float* __restrict__ pos, const int* __restrict__ sel,
    int* __restrict__ nbr, int* __restrict__ cnt,
    float* __restrict__ out_pos, float* __restrict__ out_batch)
{
    __shared__ float cd[4][CAP];
    __shared__ int   ci[4][CAP];

    const int wv   = threadIdx.x >> 6;
    const int lane = threadIdx.x & 63;
    const int c    = blockIdx.x * 4 + wv;
    const int sg   = sel[c];
    const int b    = c >> 10;            // c / MPER
    const int base = b * NPTS;
    const float* pb = pos + (size_t)base * 3;
    const float qx = pos[(size_t)sg * 3 + 0];
    const float qy = pos[(size_t)sg * 3 + 1];
    const float qz = pos[(size_t)sg * 3 + 2];

    int n = 0;
    for (int r0 = 0; r0 < NPTS; r0 += 64) {
        const int j = r0 + lane;
        float x = pb[j * 3 + 0], y = pb[j * 3 + 1], z = pb[j * 3 + 2];
        float d2 = d2f(x, y, z, qx, qy, qz);
        bool inside = ((double)d2 <= R2D);
        unsigned long long m = __ballot(inside);
        if (inside) {
            int myoff = n + __popcll(m & ((1ull << lane) - 1ull));
            if (myoff < CAP) { cd[wv][myoff] = d2; ci[wv][myoff] = j; }
        }
        n += __popcll(m);
    }
    n = min(n, CAP);
    __syncthreads();   // drain LDS writes; all waves structurally aligned here

    // rank = #{j : (dj,ij) <lex (d,id)}  -> matches lax.top_k stable ordering
    for (int i = lane; i < n; i += 64) {
        float d = cd[wv][i]; int id = ci[wv][i];
        int rank = 0;
        for (int j = 0; j < n; ++j) {
            float dj = cd[wv][j]; int ij = ci[wv][j];
            rank += (dj < d || (dj == d && ij < id)) ? 1 : 0;
        }
        if (rank < KNN) nbr[(size_t)c * KNN + rank] = base + id;
    }
    if (lane == 0) {
        cnt[c] = min(n, KNN);
        out_pos[c * 3 + 0] = qx;
        out_pos[c * 3 + 1] = qy;
        out_pos[c * 3 + 2] = qz;
        out_batch[c] = (float)b;
    }
}

// ---------------- Kernel 3: gather + MLP (67->64->64->128) + masked max ----------------
// one block per centroid, 256 threads; fp32 VALU, LDS-staged activations/weights
#define SH_INF 0            // 64*67 = 4288 floats
#define SH_W   4288         // 2048 floats (weight chunk: 32x64 or 16x128)
#define SH_H1  6336         // 64*65 = 4160 floats (stride 65 to spread banks)
#define SH_H2  10496        // 4160 floats
#define SH_TOT 14656        // 58.6 KB

__global__ __launch_bounds__(256) void mlp_kernel(
    const float* __restrict__ x, const float* __restrict__ pos,
    const int* __restrict__ nbr, const int* __restrict__ cnt,
    const float* __restrict__ out_pos,
    const float* __restrict__ W1, const float* __restrict__ b1,
    const float* __restrict__ W2, const float* __restrict__ b2,
    const float* __restrict__ W3, const float* __restrict__ b3,
    float* __restrict__ out_x)
{
    __shared__ float sm[SH_TOT];

    const int c = blockIdx.x;
    const int n = cnt[c];
    const int t = threadIdx.x;

    // ---- stage input features: inf[k][0..66] = [x[nbr_k], pos[nbr_k]-q] ----
    {
        const int k = t >> 2, g = t & 3;
        int nb = (k < n) ? nbr[(size_t)c * KNN + k] : 0;
        float q0 = out_pos[c * 3 + 0], q1 = out_pos[c * 3 + 1], q2 = out_pos[c * 3 + 2];
#pragma unroll
        for (int i = 0; i < 17; ++i) {
            int j = g + 4 * i;
            if (j < 67) {
                float v = 0.0f;
                if (k < n) {
                    if (j < 64) v = x[(size_t)nb * CIN + j];
                    else {
                        float qd = (j == 64) ? q0 : ((j == 65) ? q1 : q2);
                        v = pos[(size_t)nb * 3 + (j - 64)] - qd;   // exact fp32 sub
                    }
                }
                sm[SH_INF + k * 67 + j] = v;
            }
        }
    }

    const int tc = t & 15, tk = t >> 4;
    const int c0 = tc * 4, k0 = tk * 4;

    // ---- layer 1: 67 -> 64, ReLU ----
    float acc[4][4];
    {
        float4 bb = *(const float4*)(b1 + c0);
#pragma unroll
        for (int i = 0; i < 4; ++i) {
            acc[i][0] = bb.x; acc[i][1] = bb.y; acc[i][2] = bb.z; acc[i][3] = bb.w;
        }
        int kk0 = 0;
        for (int ch = 0; ch < 3; ++ch) {
            int rows = min(32, 67 - kk0);
            __syncthreads();
            for (int e = t; e < rows * 64; e += 256) sm[SH_W + e] = W1[kk0 * 64 + e];
            __syncthreads();
            for (int r = 0; r < rows; ++r) {
                int kk = kk0 + r;
                float4 w = *(const float4*)&sm[SH_W + r * 64 + c0];
                float in0 = sm[SH_INF + (k0 + 0) * 67 + kk];
                float in1 = sm[SH_INF + (k0 + 1) * 67 + kk];
                float in2 = sm[SH_INF + (k0 + 2) * 67 + kk];
                float in3 = sm[SH_INF + (k0 + 3) * 67 + kk];
                acc[0][0] = fmaf(in0, w.x, acc[0][0]); acc[0][1] = fmaf(in0, w.y, acc[0][1]);
                acc[0][2] = fmaf(in0, w.z, acc[0][2]); acc[0][3] = fmaf(in0, w.w, acc[0][3]);
                acc[1][0] = fmaf(in1, w.x, acc[1][0]); acc[1][1] = fmaf(in1, w.y, acc[1][1]);
                acc[1][2] = fmaf(in1, w.z, acc[1][2]); acc[1][3] = fmaf(in1, w.w, acc[1][3]);
                acc[2][0] = fmaf(in2, w.x, acc[2][0]); acc[2][1] = fmaf(in2, w.y, acc[2][1]);
                acc[2][2] = fmaf(in2, w.z, acc[2][2]); acc[2][3] = fmaf(in2, w.w, acc[2][3]);
                acc[3][0] = fmaf(in3, w.x, acc[3][0]); acc[3][1] = fmaf(in3, w.y, acc[3][1]);
                acc[3][2] = fmaf(in3, w.z, acc[3][2]); acc[3][3] = fmaf(in3, w.w, acc[3][3]);
            }
            kk0 += rows;
        }
#pragma unroll
        for (int i = 0; i < 4; ++i)
#pragma unroll
            for (int j = 0; j < 4; ++j)
                sm[SH_H1 + (k0 + i) * 65 + (c0 + j)] = fmaxf(acc[i][j], 0.0f);
    }

    // ---- layer 2: 64 -> 64, ReLU ----
    {
        float4 bb = *(const float4*)(b2 + c0);
#pragma unroll
        for (int i = 0; i < 4; ++i) {
            acc[i][0] = bb.x; acc[i][1] = bb.y; acc[i][2] = bb.z; acc[i][3] = bb.w;
        }
        for (int ch = 0; ch < 2; ++ch) {
            __syncthreads();
            for (int e = t; e < 32 * 64; e += 256) sm[SH_W + e] = W2[ch * 2048 + e];
            __syncthreads();
            for (int r = 0; r < 32; ++r) {
                int kk = ch * 32 + r;
                float4 w = *(const float4*)&sm[SH_W + r * 64 + c0];
                float in0 = sm[SH_H1 + (k0 + 0) * 65 + kk];
                float in1 = sm[SH_H1 + (k0 + 1) * 65 + kk];
                float in2 = sm[SH_H1 + (k0 + 2) * 65 + kk];
                float in3 = sm[SH_H1 + (k0 + 3) * 65 + kk];
                acc[0][0] = fmaf(in0, w.x, acc[0][0]); acc[0][1] = fmaf(in0, w.y, acc[0][1]);
                acc[0][2] = fmaf(in0, w.z, acc[0][2]); acc[0][3] = fmaf(in0, w.w, acc[0][3]);
                acc[1][0] = fmaf(in1, w.x, acc[1][0]); acc[1][1] = fmaf(in1, w.y, acc[1][1]);
                acc[1][2] = fmaf(in1, w.z, acc[1][2]); acc[1][3] = fmaf(in1, w.w, acc[1][3]);
                acc[2][0] = fmaf(in2, w.x, acc[2][0]); acc[2][1] = fmaf(in2, w.y, acc[2][1]);
                acc[2][2] = fmaf(in2, w.z, acc[2][2]); acc[2][3] = fmaf(in2, w.w, acc[2][3]);
                acc[3][0] = fmaf(in3, w.x, acc[3][0]); acc[3][1] = fmaf(in3, w.y, acc[3][1]);
                acc[3][2] = fmaf(in3, w.z, acc[3][2]); acc[3][3] = fmaf(in3, w.w, acc[3][3]);
            }
        }
        __syncthreads();
#pragma unroll
        for (int i = 0; i < 4; ++i)
#pragma unroll
            for (int j = 0; j < 4; ++j)
                sm[SH_H2 + (k0 + i) * 65 + (c0 + j)] = fmaxf(acc[i][j], 0.0f);
    }

    // ---- layer 3: 64 -> 128 (two c-tiles per thread) ----
    float acc3[2][4][4];
    {
#pragma unroll
        for (int u = 0; u < 2; ++u) {
            float4 bb = *(const float4*)(b3 + c0 + u * 64);
#pragma unroll
            for (int i = 0; i < 4; ++i) {
                acc3[u][i][0] = bb.x; acc3[u][i][1] = bb.y;
                acc3[u][i][2] = bb.z; acc3[u][i][3] = bb.w;
            }
        }
        for (int ch = 0; ch < 4; ++ch) {
            __syncthreads();
            for (int e = t; e < 16 * 128; e += 256) sm[SH_W + e] = W3[ch * 2048 + e];
            __syncthreads();
            for (int r = 0; r < 16; ++r) {
                int kk = ch * 16 + r;
                float4 wa = *(const float4*)&sm[SH_W + r * 128 + c0];
                float4 wb = *(const float4*)&sm[SH_W + r * 128 + c0 + 64];
                float in0 = sm[SH_H2 + (k0 + 0) * 65 + kk];
                float in1 = sm[SH_H2 + (k0 + 1) * 65 + kk];
                float in2 = sm[SH_H2 + (k0 + 2) * 65 + kk];
                float in3 = sm[SH_H2 + (k0 + 3) * 65 + kk];
                acc3[0][0][0] = fmaf(in0, wa.x, acc3[0][0][0]); acc3[0][0][1] = fmaf(in0, wa.y, acc3[0][0][1]);
                acc3[0][0][2] = fmaf(in0, wa.z, acc3[0][0][2]); acc3[0][0][3] = fmaf(in0, wa.w, acc3[0][0][3]);
                acc3[0][1][0] = fmaf(in1, wa.x, acc3[0][1][0]); acc3[0][1][1] = fmaf(in1, wa.y, acc3[0][1][1]);
                acc3[0][1][2] = fmaf(in1, wa.z, acc3[0][1][2]); acc3[0][1][3] = fmaf(in1, wa.w, acc3[0][1][3]);
                acc3[0][2][0] = fmaf(in2, wa.x, acc3[0][2][0]); acc3[0][2][1] = fmaf(in2, wa.y, acc3[0][2][1]);
                acc3[0][2][2] = fmaf(in2, wa.z, acc3[0][2][2]); acc3[0][2][3] = fmaf(in2, wa.w, acc3[0][2][3]);
                acc3[0][3][0] = fmaf(in3, wa.x, acc3[0][3][0]); acc3[0][3][1] = fmaf(in3, wa.y, acc3[0][3][1]);
                acc3[0][3][2] = fmaf(in3, wa.z, acc3[0][3][2]); acc3[0][3][3] = fmaf(in3, wa.w, acc3[0][3][3]);
                acc3[1][0][0] = fmaf(in0, wb.x, acc3[1][0][0]); acc3[1][0][1] = fmaf(in0, wb.y, acc3[1][0][1]);
                acc3[1][0][2] = fmaf(in0, wb.z, acc3[1][0][2]); acc3[1][0][3] = fmaf(in0, wb.w, acc3[1][0][3]);
                acc3[1][1][0] = fmaf(in1, wb.x, acc3[1][1][0]); acc3[1][1][1] = fmaf(in1, wb.y, acc3[1][1][1]);
                acc3[1][1][2] = fmaf(in1, wb.z, acc3[1][1][2]); acc3[1][1][3] = fmaf(in1, wb.w, acc3[1][1][3]);
                acc3[1][2][0] = fmaf(in2, wb.x, acc3[1][2][0]); acc3[1][2][1] = fmaf(in2, wb.y, acc3[1][2][1]);
                acc3[1][2][2] = fmaf(in2, wb.z, acc3[1][2][2]); acc3[1][2][3] = fmaf(in2, wb.w, acc3[1][2][3]);
                acc3[1][3][0] = fmaf(in3, wb.x, acc3[1][3][0]); acc3[1][3][1] = fmaf(in3, wb.y, acc3[1][3][1]);
                acc3[1][3][2] = fmaf(in3, wb.z, acc3[1][3][2]); acc3[1][3][3] = fmaf(in3, wb.w, acc3[1][3][3]);
            }
        }
    }

    // ---- masked max over k (k < n), tree-reduced via LDS partials ----
    float pm[2][4];
#pragma unroll
    for (int u = 0; u < 2; ++u)
#pragma unroll
        for (int j = 0; j < 4; ++j) pm[u][j] = -1e30f;
#pragma unroll
    for (int i = 0; i < 4; ++i) {
        if (k0 + i < n) {
#pragma unroll
            for (int u = 0; u < 2; ++u)
#pragma unroll
                for (int j = 0; j < 4; ++j) pm[u][j] = fmaxf(pm[u][j], acc3[u][i][j]);
        }
    }
    __syncthreads();   // h1 region is dead; reuse as [16][128] partials
#pragma unroll
    for (int u = 0; u < 2; ++u)
#pragma unroll
        for (int j = 0; j < 4; ++j)
            sm[SH_H1 + tk * 128 + (c0 + u * 64 + j)] = pm[u][j];
    __syncthreads();
    if (t < 128) {
        float m = sm[SH_H1 + 0 * 128 + t];
#pragma unroll
        for (int w = 1; w < 16; ++w) m = fmaxf(m, sm[SH_H1 + w * 128 + t]);
        out_x[(size_t)c * 128 + t] = m;
    }
}

extern "C" void kernel_launch(void* const* d_in, const int* in_sizes, int n_in,
                              void* d_out, int out_size, void* d_ws, size_t ws_size,
                              hipStream_t stream)
{
    const float* x   = (const float*)d_in[0];
    const float* pos = (const float*)d_in[1];
    // d_in[2] = batch (derived analytically), d_in[9] = num_graphs (constant 8)
    const float* W1 = (const float*)d_in[3];
    const float* b1 = (const float*)d_in[4];
    const float* W2 = (const float*)d_in[5];
    const float* b2 = (const float*)d_in[6];
    const float* W3 = (const float*)d_in[7];
    const float* b3 = (const float*)d_in[8];

    float* out_x     = (float*)d_out;                    // [8192,128]
    float* out_pos   = out_x + (size_t)MTOT * 128;       // [8192,3]
    float* out_batch = out_pos + (size_t)MTOT * 3;       // [8192]

    int* sel = (int*)d_ws;                               // [8192]
    int* nbr = sel + MTOT;                               // [8192*64]
    int* cnt = nbr + (size_t)MTOT * KNN;                 // [8192]

    fps_kernel<<<NB, 256, 0, stream>>>(pos, sel);
    ballq_kernel<<<MTOT / 4, 256, 0, stream>>>(pos, sel, nbr, cnt, out_pos, out_batch);
    mlp_kernel<<<MTOT, 256, 0, stream>>>(x, pos, nbr, cnt, out_pos,
                                         W1, b1, W2, b2, W3, b3, out_x);
}

// Round 4
// 767.324 us; speedup vs baseline: 1.8381x; 1.8381x over previous
//
#include <hip/hip_runtime.h>
#include <math.h>

#define NB   8
#define NPTS 4096
#define MPER 1024
#define MTOT (NB*MPER)
#define CIN  64
#define KNN  64
#define CAP  512
// (0.2*0.2) computed in double, as the reference's python-float R*R
#define R2D  0.04000000000000001

typedef unsigned int u32;
typedef unsigned long long u64;
using s16x8 = __attribute__((ext_vector_type(8))) short;   // 8 bf16 (4 VGPRs)
using f32x4 = __attribute__((ext_vector_type(4))) float;

// exact IEEE fp32 distance, reference order: ((dx*dx + dy*dy) + dz*dz), no FMA
__device__ __forceinline__ float d2f(float ax, float ay, float az,
                                     float bx, float by, float bz) {
    float dx = __fsub_rn(ax, bx);
    float dy = __fsub_rn(ay, by);
    float dz = __fsub_rn(az, bz);
    return __fadd_rn(__fadd_rn(__fmul_rn(dx, dx), __fmul_rn(dy, dy)),
                     __fmul_rn(dz, dz));
}

// float -> bf16 bits, round-to-nearest-even (finite inputs only)
__device__ __forceinline__ unsigned short f2bf(float f) {
    u32 x = __float_as_uint(f);
    u32 r = (x + 0x7fffu + ((x >> 16) & 1u)) >> 16;
    return (unsigned short)r;
}
__device__ __forceinline__ u32 pk2(float a, float b) {
    return (u32)f2bf(a) | ((u32)f2bf(b) << 16);
}

__device__ __forceinline__ f32x4 mfma16(s16x8 a, s16x8 b, f32x4 c) {
    return __builtin_amdgcn_mfma_f32_16x16x32_bf16(a, b, c, 0, 0, 0);
}

// full-wave (64-lane) max reduction of a u64 key via DPP; result valid in lane 63.
__device__ __forceinline__ unsigned long long wave_max_u64_dpp(unsigned long long key)
{
#define DPPMAX(ctrl, rmask) do {                                                   \
        unsigned int lo_ = (unsigned int)key;                                      \
        unsigned int hi_ = (unsigned int)(key >> 32);                              \
        unsigned int plo = (unsigned int)__builtin_amdgcn_update_dpp(              \
            0, (int)lo_, ctrl, rmask, 0xf, false);                                 \
        unsigned int phi = (unsigned int)__builtin_amdgcn_update_dpp(              \
            0, (int)hi_, ctrl, rmask, 0xf, false);                                 \
        unsigned long long pk = ((unsigned long long)phi << 32) | plo;             \
        if (pk > key) key = pk;                                                    \
    } while (0)
    DPPMAX(0x111, 0xf);   // row_shr:1
    DPPMAX(0x112, 0xf);   // row_shr:2
    DPPMAX(0x114, 0xf);   // row_shr:4
    DPPMAX(0x118, 0xf);   // row_shr:8
    DPPMAX(0x142, 0xa);   // row_bcast:15 -> rows 1,3
    DPPMAX(0x143, 0xc);   // row_bcast:31 -> rows 2,3
#undef DPPMAX
    return key;
}

// ---------------- Kernel 1: farthest point sampling (round-2 version, 617us) ----
__global__ __launch_bounds__(256) void fps_kernel(const float* __restrict__ pos,
                                                  int* __restrict__ sel)
{
    const int b    = blockIdx.x;
    const int t    = threadIdx.x;
    const int lane = t & 63;
    const int wv   = t >> 6;
    const float* pb = pos + (size_t)b * NPTS * 3;

    __shared__ float lx[NPTS], ly[NPTS], lz[NPTS];
    __shared__ unsigned long long part[2][4];

    float px[16], py[16], pz[16], mind[16];
#pragma unroll
    for (int r = 0; r < 16; ++r) {
        int j = r * 256 + t;
        float x = pb[j * 3 + 0];
        float y = pb[j * 3 + 1];
        float z = pb[j * 3 + 2];
        px[r] = x; py[r] = y; pz[r] = z;
        mind[r] = 3.0e38f;   // first fmin yields exactly d2-to-p0
        lx[j] = x; ly[j] = y; lz[j] = z;
    }
    if (t == 0) sel[b * MPER + 0] = b * NPTS + 0;
    __syncthreads();

    float cx = lx[0], cy = ly[0], cz = lz[0];

    for (int it = 1; it < MPER; ++it) {
        float bv = -1.0f; int bi = 0;
#pragma unroll
        for (int r = 0; r < 16; ++r) {
            float d2 = d2f(px[r], py[r], pz[r], cx, cy, cz);
            float m = fminf(mind[r], d2);
            mind[r] = m;
            if (m > bv) { bv = m; bi = r * 256 + t; }
        }
        unsigned long long key =
            ((unsigned long long)__float_as_uint(bv) << 32) | (unsigned int)(~bi);
        key = wave_max_u64_dpp(key);

        const int p = it & 1;
        if (lane == 63) part[p][wv] = key;
        __syncthreads();

        unsigned long long k0 = part[p][0];
        unsigned long long k1 = part[p][1];
        unsigned long long k2 = part[p][2];
        unsigned long long k3 = part[p][3];
        unsigned long long ka = k0 > k1 ? k0 : k1;
        unsigned long long kb = k2 > k3 ? k2 : k3;
        unsigned long long km = ka > kb ? ka : kb;
        int pick = (int)(~(u32)km);

        cx = lx[pick]; cy = ly[pick]; cz = lz[pick];
        if (t == 0) sel[b * MPER + it] = b * NPTS + pick;
    }
}

// ---------------- Kernel 2: ball query + K nearest (rank select) ----------------
__global__ __launch_bounds__(256) void ballq_kernel(
    const float* __restrict__ pos, const int* __restrict__ sel,
    int* __restrict__ nbr, int* __restrict__ cnt,
    float* __restrict__ out_pos, float* __restrict__ out_batch)
{
    __shared__ float cd[4][CAP];
    __shared__ int   ci[4][CAP];

    const int wv   = threadIdx.x >> 6;
    const int lane = threadIdx.x & 63;
    const int c    = blockIdx.x * 4 + wv;
    const int sg   = sel[c];
    const int b    = c >> 10;            // c / MPER
    const int base = b * NPTS;
    const float* pb = pos + (size_t)base * 3;
    const float qx = pos[(size_t)sg * 3 + 0];
    const float qy = pos[(size_t)sg * 3 + 1];
    const float qz = pos[(size_t)sg * 3 + 2];

    int n = 0;
    for (int r0 = 0; r0 < NPTS; r0 += 64) {
        const int j = r0 + lane;
        float x = pb[j * 3 + 0], y = pb[j * 3 + 1], z = pb[j * 3 + 2];
        float d2 = d2f(x, y, z, qx, qy, qz);
        bool inside = ((double)d2 <= R2D);
        unsigned long long m = __ballot(inside);
        if (inside) {
            int myoff = n + __popcll(m & ((1ull << lane) - 1ull));
            if (myoff < CAP) { cd[wv][myoff] = d2; ci[wv][myoff] = j; }
        }
        n += __popcll(m);
    }
    n = min(n, CAP);
    __syncthreads();

    for (int i = lane; i < n; i += 64) {
        float d = cd[wv][i]; int id = ci[wv][i];
        int rank = 0;
        for (int j = 0; j < n; ++j) {
            float dj = cd[wv][j]; int ij = ci[wv][j];
            rank += (dj < d || (dj == d && ij < id)) ? 1 : 0;
        }
        if (rank < KNN) nbr[(size_t)c * KNN + rank] = base + id;
    }
    if (lane == 0) {
        cnt[c] = min(n, KNN);
        out_pos[c * 3 + 0] = qx;
        out_pos[c * 3 + 1] = qy;
        out_pos[c * 3 + 2] = qz;
        out_batch[c] = (float)b;
    }
}

// ---------------- weight prep: bf16 transposed+padded weights into ws ----------
// ws layout (ushort units): W1t[64][104] | W2t[64][72] | W3t[128][72]
#define W1T_U 6656
#define W2T_U 4608
#define W3T_U 9216
#define WTOT_U 20480

__global__ __launch_bounds__(256) void prep_weights(
    const float* __restrict__ W1, const float* __restrict__ W2,
    const float* __restrict__ W3, unsigned short* __restrict__ wsW)
{
    int i = blockIdx.x * 256 + threadIdx.x;
    if (i >= WTOT_U) return;
    float v;
    if (i < W1T_U) {
        int cr = i / 104, k = i - cr * 104;
        v = (k < 67) ? W1[k * 64 + cr] : 0.0f;
    } else if (i < W1T_U + W2T_U) {
        int j = i - W1T_U;
        int cr = j / 72, k = j - cr * 72;
        v = (k < 64) ? W2[k * 64 + cr] : 0.0f;
    } else {
        int j = i - (W1T_U + W2T_U);
        int cr = j / 72, k = j - cr * 72;
        v = (k < 64) ? W3[k * 128 + cr] : 0.0f;
    }
    wsW[i] = f2bf(v);
}

// ---------------- Kernel 3: gather + MFMA MLP + masked max ---------------------
// one block per centroid, 256 threads = 4 waves; wave w owns output rows
// [16w,16w+16). mfma_f32_16x16x32_bf16: A-frag lane l = A[l&15][(l>>4)*8+j],
// B-frag lane l = B[(l>>4)*8+j][l&15] (stored transposed, rows contiguous),
// D lane l reg r = D[(l>>4)*4+r][l&15]  (m89-verified layout).
__global__ __launch_bounds__(256) void mlp_kernel(
    const float* __restrict__ x, const float* __restrict__ pos,
    const int* __restrict__ nbr, const int* __restrict__ cnt,
    const float* __restrict__ out_pos,
    const unsigned short* __restrict__ wsW,
    const float* __restrict__ b1, const float* __restrict__ b2,
    const float* __restrict__ b3,
    float* __restrict__ out_x)
{
    __shared__ __align__(16) unsigned short smA[6656];   // A1[64][104]; later H2[64][72]; later f32 partial[4][128]
    __shared__ __align__(16) unsigned short smW[WTOT_U]; // W1t (later H1[64][72]) | W2t | W3t

    const int c = blockIdx.x;
    const int t = threadIdx.x;
    const int n = cnt[c];

    // ---- stage weights ws -> LDS (linear, 40960 B) ----
    {
        const uint4* src = (const uint4*)wsW;
        uint4* dst = (uint4*)smW;
#pragma unroll
        for (int i = 0; i < 10; ++i) dst[t + 256 * i] = src[t + 256 * i];
    }

    // ---- stage A1: row k = [bf16(x[nb][0..64)), bf16(pos[nb]-q), zeros] ----
    {
        const int k = t >> 2, g = t & 3;
        const bool valid = k < n;
        const int nb = valid ? nbr[(size_t)c * KNN + k] : 0;
        const float* xr = x + (size_t)nb * CIN + g * 16;
        float4 f0, f1, f2, f3;
        if (valid) {
            f0 = *(const float4*)(xr + 0);
            f1 = *(const float4*)(xr + 4);
            f2 = *(const float4*)(xr + 8);
            f3 = *(const float4*)(xr + 12);
        } else {
            f0 = float4{0.f, 0.f, 0.f, 0.f};
            f1 = f0; f2 = f0; f3 = f0;
        }
        uint4 ua = { pk2(f0.x, f0.y), pk2(f0.z, f0.w), pk2(f1.x, f1.y), pk2(f1.z, f1.w) };
        uint4 ub = { pk2(f2.x, f2.y), pk2(f2.z, f2.w), pk2(f3.x, f3.y), pk2(f3.z, f3.w) };
        *(uint4*)&smA[k * 104 + g * 16 + 0] = ua;
        *(uint4*)&smA[k * 104 + g * 16 + 8] = ub;
        if (g == 0) {
            float r0 = 0.f, r1 = 0.f, r2 = 0.f;
            if (valid) {
                float q0 = out_pos[c * 3 + 0];
                float q1 = out_pos[c * 3 + 1];
                float q2 = out_pos[c * 3 + 2];
                r0 = __fsub_rn(pos[(size_t)nb * 3 + 0], q0);
                r1 = __fsub_rn(pos[(size_t)nb * 3 + 1], q1);
                r2 = __fsub_rn(pos[(size_t)nb * 3 + 2], q2);
            }
            uint4 uz = { 0u, 0u, 0u, 0u };
            uint4 ur = { pk2(r0, r1), (u32)f2bf(r2), 0u, 0u };
            *(uint4*)&smA[k * 104 + 64] = ur;
            *(uint4*)&smA[k * 104 + 72] = uz;
            *(uint4*)&smA[k * 104 + 80] = uz;
            *(uint4*)&smA[k * 104 + 88] = uz;
            *(uint4*)&smA[k * 104 + 96] = uz;
        }
    }
    __syncthreads();

    const int l  = t & 63;
    const int w  = t >> 6;
    const int lr = l & 15;
    const int kg = l >> 4;

    float bias1[4], bias2[4];
#pragma unroll
    for (int nt = 0; nt < 4; ++nt) {
        bias1[nt] = b1[nt * 16 + lr];
        bias2[nt] = b2[nt * 16 + lr];
    }

    const unsigned short* W1t = smW;                    // stride 104
    const unsigned short* W2t = smW + W1T_U;            // stride 72
    const unsigned short* W3t = smW + W1T_U + W2T_U;    // stride 72
    unsigned short* H1 = smW;                           // [64][72] overlays W1t
    unsigned short* H2 = smA;                           // [64][72] overlays A1

    // ---- layer 1: A1[64][96+] x W1t -> H1 (relu) ----
    f32x4 acc1[4];
#pragma unroll
    for (int nt = 0; nt < 4; ++nt) acc1[nt] = f32x4{0.f, 0.f, 0.f, 0.f};
    {
        const int ao = (w * 16 + lr) * 104 + kg * 8;
        const int bo = lr * 104 + kg * 8;
#pragma unroll
        for (int kc = 0; kc < 3; ++kc) {
            s16x8 af = *(const s16x8*)&smA[ao + kc * 32];
#pragma unroll
            for (int nt = 0; nt < 4; ++nt) {
                s16x8 bf = *(const s16x8*)&W1t[bo + nt * 1664 + kc * 32];
                acc1[nt] = mfma16(af, bf, acc1[nt]);
            }
        }
    }
    __syncthreads();   // all W1t/A1 reads complete before overlaying W1t with H1
#pragma unroll
    for (int nt = 0; nt < 4; ++nt) {
        const int col = nt * 16 + lr;
#pragma unroll
        for (int r = 0; r < 4; ++r) {
            const int row = w * 16 + kg * 4 + r;
            float v = fmaxf(acc1[nt][r] + bias1[nt], 0.0f);
            H1[row * 72 + col] = f2bf(v);
        }
    }
    __syncthreads();

    // ---- layer 2: H1 x W2t -> H2 (relu) ----
    f32x4 acc2[4];
#pragma unroll
    for (int nt = 0; nt < 4; ++nt) acc2[nt] = f32x4{0.f, 0.f, 0.f, 0.f};
    {
        const int ao = (w * 16 + lr) * 72 + kg * 8;
        const int bo = lr * 72 + kg * 8;
#pragma unroll
        for (int kc = 0; kc < 2; ++kc) {
            s16x8 af = *(const s16x8*)&H1[ao + kc * 32];
#pragma unroll
            for (int nt = 0; nt < 4; ++nt) {
                s16x8 bf = *(const s16x8*)&W2t[bo + nt * 1152 + kc * 32];
                acc2[nt] = mfma16(af, bf, acc2[nt]);
            }
        }
    }
    // H2 overlays A1 (dead since layer-1 barrier); disjoint from H1/W2t -> no
    // barrier needed before these writes, only after (visibility for layer 3).
#pragma unroll
    for (int nt = 0; nt < 4; ++nt) {
        const int col = nt * 16 + lr;
#pragma unroll
        for (int r = 0; r < 4; ++r) {
            const int row = w * 16 + kg * 4 + r;
            float v = fmaxf(acc2[nt][r] + bias2[nt], 0.0f);
            H2[row * 72 + col] = f2bf(v);
        }
    }
    __syncthreads();

    // ---- layer 3: H2 x W3t -> acc3 (64x128 per block) ----
    f32x4 acc3[8];
#pragma unroll
    for (int nt = 0; nt < 8; ++nt) acc3[nt] = f32x4{0.f, 0.f, 0.f, 0.f};
    {
        const int ao = (w * 16 + lr) * 72 + kg * 8;
        const int bo = lr * 72 + kg * 8;
#pragma unroll
        for (int kc = 0; kc < 2; ++kc) {
            s16x8 af = *(const s16x8*)&H2[ao + kc * 32];
#pragma unroll
            for (int nt = 0; nt < 8; ++nt) {
                s16x8 bf = *(const s16x8*)&W3t[bo + nt * 1152 + kc * 32];
                acc3[nt] = mfma16(af, bf, acc3[nt]);
            }
        }
    }

    // ---- masked max over valid rows; bias added after max (column-constant) ----
    float pm[8];
#pragma unroll
    for (int nt = 0; nt < 8; ++nt) pm[nt] = -1e30f;
#pragma unroll
    for (int r = 0; r < 4; ++r) {
        const int row = w * 16 + kg * 4 + r;
        if (row < n) {
#pragma unroll
            for (int nt = 0; nt < 8; ++nt) pm[nt] = fmaxf(pm[nt], acc3[nt][r]);
        }
    }
#pragma unroll
    for (int nt = 0; nt < 8; ++nt) {
        pm[nt] = fmaxf(pm[nt], __shfl_xor(pm[nt], 16));
        pm[nt] = fmaxf(pm[nt], __shfl_xor(pm[nt], 32));
    }
    __syncthreads();   // all layer-3 LDS reads done; reuse smA as f32 partials
    float* pbuf = (float*)smA;            // [4][128]
    if (kg == 0) {
#pragma unroll
        for (int nt = 0; nt < 8; ++nt) pbuf[w * 128 + nt * 16 + lr] = pm[nt];
    }
    __syncthreads();
    if (t < 128) {
        float m = fmaxf(fmaxf(pbuf[t], pbuf[128 + t]),
                        fmaxf(pbuf[256 + t], pbuf[384 + t]));
        out_x[(size_t)c * 128 + t] = m + b3[t];
    }
}

extern "C" void kernel_launch(void* const* d_in, const int* in_sizes, int n_in,
                              void* d_out, int out_size, void* d_ws, size_t ws_size,
                              hipStream_t stream)
{
    const float* x   = (const float*)d_in[0];
    const float* pos = (const float*)d_in[1];
    const float* W1 = (const float*)d_in[3];
    const float* b1 = (const float*)d_in[4];
    const float* W2 = (const float*)d_in[5];
    const float* b2 = (const float*)d_in[6];
    const float* W3 = (const float*)d_in[7];
    const float* b3 = (const float*)d_in[8];

    float* out_x     = (float*)d_out;                    // [8192,128]
    float* out_pos   = out_x + (size_t)MTOT * 128;       // [8192,3]
    float* out_batch = out_pos + (size_t)MTOT * 3;       // [8192]

    int* sel = (int*)d_ws;                               // [8192]
    int* nbr = sel + MTOT;                               // [8192*64]
    int* cnt = nbr + (size_t)MTOT * KNN;                 // [8192]
    unsigned short* wsW = (unsigned short*)(cnt + MTOT); // [20480] bf16 weights

    prep_weights<<<(WTOT_U + 255) / 256, 256, 0, stream>>>(W1, W2, W3, wsW);
    fps_kernel<<<NB, 256, 0, stream>>>(pos, sel);
    ballq_kernel<<<MTOT / 4, 256, 0, stream>>>(pos, sel, nbr, cnt, out_pos, out_batch);
    mlp_kernel<<<MTOT, 256, 0, stream>>>(x, pos, nbr, cnt, out_pos, wsW,
                                         b1, b2, b3, out_x);
}